// Round 14
// baseline (231.639 us; speedup 1.0000x reference)
//
#include <hip/hip_runtime.h>
#include <hip/hip_fp16.h>

#define BB 8
#define LL 1024
#define DIN 256
#define DM 512
#define HH 8
#define DH 64

typedef __attribute__((ext_vector_type(8))) short bf16x8;
typedef __attribute__((ext_vector_type(4))) float f32x4;

__device__ __forceinline__ unsigned short f2bf(float f) {
  union { float f; unsigned u; } c; c.f = f;
  unsigned u = c.u;
  return (unsigned short)((u + 0x7fffu + ((u >> 16) & 1u)) >> 16);
}

#if defined(__has_builtin)
#if __has_builtin(__builtin_amdgcn_cvt_pk_bf16_f32)
#define HAS_PK_BF16 1
#endif
#endif

#if defined(HAS_PK_BF16)
typedef __bf16 bf2 __attribute__((ext_vector_type(2)));
__device__ __forceinline__ unsigned pk2(float lo, float hi) {
  union { bf2 v; unsigned u; } c;
  c.v = __builtin_amdgcn_cvt_pk_bf16_f32(lo, hi);
  return c.u;
}
#else
__device__ __forceinline__ unsigned pk2(float lo, float hi) {
  return ((unsigned)f2bf(hi) << 16) | f2bf(lo);
}
#endif

// 16-bit bias pack: dis as f16 rounded to the 15-bit (even-LSB) grid,
// binary adj in the stolen LSB (validated r12/r13: absmax unchanged).
__device__ __forceinline__ unsigned pk16(float a, float d) {
  unsigned v = (unsigned)__half_as_ushort(__float2half_rn(d));
  v = (v + 1u) & 0xFFFEu;           // round-to-nearest on 15-bit grid
  return v | (a > 0.5f ? 1u : 0u);
}
__device__ __forceinline__ unsigned pk16x2(float a0, float d0,
                                           float a1, float d1) {
  return pk16(a0, d0) | (pk16(a1, d1) << 16);
}

// async global -> LDS DMA, 16 B/lane; LDS dest = wave-uniform base + lane*16
__device__ __forceinline__ void async_copy16(void* lds, const void* g) {
  __builtin_amdgcn_global_load_lds(
      (const __attribute__((address_space(1))) unsigned*)g,
      (__attribute__((address_space(3))) unsigned*)lds, 16, 0, 0);
}

// ---------------- K0: merged precast (u16 bias pack) ----------------
__global__ __launch_bounds__(256) void prep(
    const float* __restrict__ qin, const float* __restrict__ kin,
    const float* __restrict__ vin,
    const float* __restrict__ wq, const float* __restrict__ wk,
    const float* __restrict__ wv, const float* __restrict__ wo,
    const int* __restrict__ msk,
    const float* __restrict__ adj, const float* __restrict__ dis,
    unsigned short* __restrict__ xq, unsigned short* __restrict__ xk,
    unsigned short* __restrict__ xv,
    unsigned short* __restrict__ wqb, unsigned short* __restrict__ wkb,
    unsigned short* __restrict__ wvb, unsigned short* __restrict__ wob,
    float* __restrict__ mad, unsigned short* __restrict__ bp)
{
  int t = blockIdx.x * 256 + threadIdx.x;
  const int XS = 524288, WS = 32768;
  if (t < 3 * XS) {
    int seg = t >> 19, off = t & (XS - 1);
    const float* s = (seg == 0) ? qin : (seg == 1) ? kin : vin;
    unsigned short* d = (seg == 0) ? xq : (seg == 1) ? xk : xv;
    float4 f = ((const float4*)s)[off];
    uint2 o = { pk2(f.x, f.y), pk2(f.z, f.w) };
    ((uint2*)d)[off] = o;
    return;
  }
  t -= 3 * XS;
  if (t < 3 * WS) {
    int seg = t >> 15, off = t & (WS - 1);
    const float* s = (seg == 0) ? wq : (seg == 1) ? wk : wv;
    unsigned short* d = (seg == 0) ? wqb : (seg == 1) ? wkb : wvb;
    float4 f = ((const float4*)s)[off];
    uint2 o = { pk2(f.x, f.y), pk2(f.z, f.w) };
    ((uint2*)d)[off] = o;
    return;
  }
  t -= 3 * WS;
  if (t < 65536) {
    float4 f = ((const float4*)wo)[t];
    uint2 o = { pk2(f.x, f.y), pk2(f.z, f.w) };
    ((uint2*)wob)[t] = o;
    return;
  }
  t -= 65536;
  if (t < 2048) {
    int4 m = ((const int4*)msk)[t];
    float4 f = { m.x ? 0.0f : -30000.0f, m.y ? 0.0f : -30000.0f,
                 m.z ? 0.0f : -30000.0f, m.w ? 0.0f : -30000.0f };
    ((float4*)mad)[t] = f;
    return;
  }
  t -= 2048;  // u16 bias pack: 1,048,576 threads x 8 elements
  if (t < 1048576) {
    float4 a0 = ((const float4*)adj)[t * 2];
    float4 a1 = ((const float4*)adj)[t * 2 + 1];
    float4 d0 = ((const float4*)dis)[t * 2];
    float4 d1 = ((const float4*)dis)[t * 2 + 1];
    uint4 o = { pk16x2(a0.x, d0.x, a0.y, d0.y),
                pk16x2(a0.z, d0.z, a0.w, d0.w),
                pk16x2(a1.x, d1.x, a1.y, d1.y),
                pk16x2(a1.z, d1.z, a1.w, d1.w) };
    ((uint4*)bp)[t] = o;
  }
}

// ---------------- K1: QKV projection, barrier-free K-loop (r10) ------------
__global__ __launch_bounds__(256) void qkv_proj(
    const unsigned short* __restrict__ xq, const unsigned short* __restrict__ xk,
    const unsigned short* __restrict__ xv,
    const unsigned short* __restrict__ wqb, const unsigned short* __restrict__ wkb,
    const unsigned short* __restrict__ wvb,
    unsigned short* __restrict__ qb, unsigned short* __restrict__ kb,
    unsigned short* __restrict__ vt)
{
  const int t = blockIdx.z;
  const unsigned short* __restrict__ X = (t == 0) ? xq : (t == 1) ? xk : xv;
  const unsigned short* __restrict__ W = (t == 0) ? wqb : (t == 1) ? wkb : wvb;
  const int m0 = blockIdx.y * 128;
  const int h  = blockIdx.x;
  // arena: W static 32768 | X 4 waves x (2 parity x 2048) = 49152 B
  __shared__ __align__(16) char arena[49152];
  const int tid = threadIdx.x;
  const int wid = tid >> 6;
  const int lane = tid & 63;
  const int lo = lane & 15;
  const int quad = lane >> 4;
  char* xpriv = arena + 32768 + wid * 4096;

  f32x4 acc[2][4];
#pragma unroll
  for (int mi = 0; mi < 2; ++mi)
#pragma unroll
    for (int ni = 0; ni < 4; ++ni) acc[mi][ni] = (f32x4)0.0f;

#pragma unroll
  for (int j = 0; j < 8; ++j) {
    int idx = j * 256 + tid, r = idx >> 5, c = idx & 31;
    async_copy16(arena + j * 4096 + wid * 1024,
                 W + (size_t)(h * 64 + r) * DIN + ((c ^ (r & 15)) * 8));
  }
#pragma unroll
  for (int j = 0; j < 2; ++j) {
    int idx = j * 64 + lane, r = idx >> 2, c = idx & 3;
    async_copy16(xpriv + j * 1024,
                 X + (size_t)(m0 + wid * 32 + r) * DIN + ((c ^ (r & 3)) * 8));
  }
  __syncthreads();  // drains W + X(0); the only barrier

  const unsigned short* Wb = (const unsigned short*)arena;
  for (int it = 0; it < 8; ++it) {
    const int p = it & 1;
    if (it < 7) {
      const int kk = (it + 1) * 32;
#pragma unroll
      for (int j = 0; j < 2; ++j) {
        int idx = j * 64 + lane, r = idx >> 2, c = idx & 3;
        async_copy16(xpriv + (1 - p) * 2048 + j * 1024,
                     X + (size_t)(m0 + wid * 32 + r) * DIN + kk +
                         ((c ^ (r & 3)) * 8));
      }
      asm volatile("" ::: "memory");
      asm volatile("s_waitcnt vmcnt(2)" ::: "memory");
    } else {
      asm volatile("s_waitcnt vmcnt(0)" ::: "memory");
    }
    const unsigned short* Ab = (const unsigned short*)(xpriv + p * 2048);
    bf16x8 a[2], bfr[4];
#pragma unroll
    for (int mi = 0; mi < 2; ++mi) {
      int R = mi * 16 + lo;
      a[mi] = *(const bf16x8*)&Ab[R * 32 + ((quad ^ (R & 3)) * 8)];
    }
#pragma unroll
    for (int ni = 0; ni < 4; ++ni) {
      int N = ni * 16 + lo;
      bfr[ni] = *(const bf16x8*)&Wb[N * 256 + (((it * 4 + quad) ^ (N & 15)) * 8)];
    }
#pragma unroll
    for (int mi = 0; mi < 2; ++mi)
#pragma unroll
      for (int ni = 0; ni < 4; ++ni)
        acc[mi][ni] = __builtin_amdgcn_mfma_f32_16x16x32_bf16(
            a[mi], bfr[ni], acc[mi][ni], 0, 0, 0);
  }

  const int b = m0 >> 10;
  const int lbase0 = (m0 & 1023) + wid * 32;
  if (t < 2) {
    unsigned short* dstp = (t == 0) ? qb : kb;
#pragma unroll
    for (int mi = 0; mi < 2; ++mi)
#pragma unroll
      for (int ni = 0; ni < 4; ++ni) {
        int d = ni * 16 + lo;
#pragma unroll
        for (int r = 0; r < 4; ++r) {
          int lb = lbase0 + mi * 16 + quad * 4 + r;
          dstp[((size_t)(b * HH + h) * LL + lb) * DH + d] = f2bf(acc[mi][ni][r]);
        }
      }
  } else {
#pragma unroll
    for (int mi = 0; mi < 2; ++mi)
#pragma unroll
      for (int ni = 0; ni < 4; ++ni) {
        int d = ni * 16 + lo;
        int lb = lbase0 + quad * 8 + mi * 4;  // phi-permuted within 32-block
        uint2 o = { pk2(acc[mi][ni][0], acc[mi][ni][1]),
                    pk2(acc[mi][ni][2], acc[mi][ni][3]) };
        *(uint2*)&vt[((size_t)(b * HH + h) * DH + d) * LL + lb] = o;
      }
  }
}

// ---------------- K2: attn, QBLK=64 (2x work per K-tile) -------------------
// r13 minimum-LDS wave-private pipeline with 64 q-rows per block (nj 2->4):
// per-tile FIXED costs (K-DMA chain, bias DMA, vmcnt waits, V/mask issue)
// unchanged while per-tile compute doubles — amortizes the ~40% per-tile
// idle that survived r8 (barrier), r12 (bytes), r13 (occupancy) refutations.
// Grid 512: idx = qt*32 + hg*8 + b, q0 = qt*64. 4 waves: (h, kh) as before.
// K single-buffered wave-private 4KB (overwrite after lgkmcnt(0)); bias u16
// dbuf 2x4KB staged one tile ahead. vmcnt audit: tile-top FIFO (worst case)
// = [K(t) 4 | bias(t+1) 4 | V+mask(t) 6] = 14 -> vmcnt(8) retires >= K(t)
// (bias(t) is older than K(t) => transitively retired); last tile: [K 4 |
// V+mask 6] = 10 -> vmcnt(6). arena = K 4x4096 + bias 4x8192 = 49152 B.
__global__ __launch_bounds__(256) void attn(
    const unsigned short* __restrict__ qb, const unsigned short* __restrict__ kb,
    const unsigned short* __restrict__ vt,
    const float* __restrict__ mad, const unsigned short* __restrict__ bp,
    const float* __restrict__ la_, const float* __restrict__ ld_,
    unsigned short* __restrict__ ao)
{
  const int bi = blockIdx.x;
  const int b  = bi & 7;
  const int hg = (bi >> 3) & 3;
  const int q0 = (bi >> 5) * 64;
  const int tid = threadIdx.x;
  const int wid = tid >> 6;
  const int lane = tid & 63;
  const int lo = lane & 15;
  const int quad = lane >> 4;
  const int h  = hg * 2 + (wid & 1);
  const int kh = wid >> 1;
  const int bh = b * HH + h;

  // arena: K single 4x4096 | bias dbuf 4x(2x4096) = 49152 B; merge alias after
  __shared__ __align__(16) char arena[49152];
  char* kpriv = arena + wid * 4096;            // wave-private single K buf
  char* bpriv = arena + 16384 + wid * 8192;    // wave-private bias, 2 parities
  float* mgbuf = (float*)arena;  // merge alias (post-loop, staging dead)

  const float LOG2E = 1.44269504f;
  const float la2 = la_[h] * LOG2E, ld2 = ld_[h] * LOG2E;
  const float sc2 = 0.125f * LOG2E;

  const unsigned short* qp = qb + ((size_t)bh * LL + q0) * DH;
  bf16x8 qB[4][2];
#pragma unroll
  for (int nj = 0; nj < 4; ++nj)
#pragma unroll
    for (int ki = 0; ki < 2; ++ki)
      qB[nj][ki] = *(const bf16x8*)&qp[(nj * 16 + lo) * DH + ki * 32 + quad * 8];

  const unsigned short* kp = kb + (size_t)bh * LL * DH;
  const unsigned short* vp = vt + (size_t)bh * DH * LL;
  const unsigned short* bpp = bp + ((size_t)b * LL + q0) * LL;
  const float* mp = mad + b * LL;

  f32x4 o[4][4];
  float rs[4] = {0.0f, 0.0f, 0.0f, 0.0f};
#pragma unroll
  for (int md = 0; md < 4; ++md)
#pragma unroll
    for (int nj = 0; nj < 4; ++nj) o[md][nj] = (f32x4)0.0f;

  const int kbeg = kh * (LL / 2);
  const int r8 = lane >> 3, p8 = lane & 7;
  const int br = lane >> 2;            // bias row within 16-row group
  const int bsw = ((((lane & 3) << 1) ^ (br & 6)) << 2);  // u16 col, swizzled

  // prologue: bias(0) -> parity 0 (4 ops), K(0) -> single buf (4 ops)
  {
    const unsigned short* bg = bpp + kh * (LL / 2);
#pragma unroll
    for (int j = 0; j < 4; ++j)
      async_copy16(bpriv + j * 1024, bg + (size_t)(j * 16 + br) * LL + bsw);
    const unsigned short* kg = kp + (size_t)kbeg * DH;
#pragma unroll
    for (int j = 0; j < 4; ++j)
      async_copy16(kpriv + j * 1024, kg + (j * 8 + r8) * 64 + ((p8 ^ r8) * 8));
  }
  // no barrier: wave-private staging, readiness via counted vmcnt

  for (int jt = 0; jt < 16; ++jt) {
    const int p = jt & 1;
    const int k0 = kbeg + jt * 32;

    // A: bias(t+1) DMA into alt parity (full-tile latency cover for HBM)
    if (jt < 15) {
      const unsigned short* bg = bpp + kh * (LL / 2) + (jt + 1) * 32;
#pragma unroll
      for (int j = 0; j < 4; ++j)
        async_copy16(bpriv + (1 - p) * 4096 + j * 1024,
                     bg + (size_t)(j * 16 + br) * LL + bsw);
    }

    // B: V (phi-ordered, 16B) + mask for THIS tile
    bf16x8 vA[4];
#pragma unroll
    for (int md = 0; md < 4; ++md)
      vA[md] = *(const bf16x8*)&vp[(md * 16 + lo) * LL + k0 + quad * 8];
    f32x4 msv[2];
#pragma unroll
    for (int mi = 0; mi < 2; ++mi)
      msv[mi] = *(const f32x4*)&mp[k0 + mi * 16 + quad * 4];
    asm volatile("" ::: "memory");

    // C: retire K(t) (+ bias(t), older in FIFO)
    if (jt < 15) {
      asm volatile("s_waitcnt vmcnt(8)" ::: "memory");
    } else {
      asm volatile("s_waitcnt vmcnt(6)" ::: "memory");
    }

    // D: all LDS reads for this tile -> regs
    bf16x8 kA[2][2];
#pragma unroll
    for (int mi = 0; mi < 2; ++mi)
#pragma unroll
      for (int ki = 0; ki < 2; ++ki)
        kA[mi][ki] = *(const bf16x8*)&((const unsigned short*)kpriv)
            [(mi * 16 + lo) * 64 + (((ki * 4 + quad) ^ (lo & 7)) * 8)];
    const unsigned short* bbf = (const unsigned short*)(bpriv + p * 4096);
    uint2 w[2][4];
#pragma unroll
    for (int mi = 0; mi < 2; ++mi)
#pragma unroll
      for (int nj = 0; nj < 4; ++nj)
        w[mi][nj] = *(const uint2*)&bbf[(nj * 16 + lo) * 32 +
                                        (((mi * 4 + quad) ^ (lo & 6)) << 2)];

    // E: LDS reads drained -> safe to overwrite single K buf with K(t+1)
    asm volatile("s_waitcnt lgkmcnt(0)" ::: "memory");
    if (jt < 15) {
      const unsigned short* kg = kp + (size_t)(k0 + 32) * DH;
#pragma unroll
      for (int j = 0; j < 4; ++j)
        async_copy16(kpriv + j * 1024,
                     kg + (j * 8 + r8) * 64 + ((p8 ^ r8) * 8));
    }
    asm volatile("" ::: "memory");

    // QK^T (register operands only)
    f32x4 s[2][4];
#pragma unroll
    for (int mi = 0; mi < 2; ++mi)
#pragma unroll
      for (int nj = 0; nj < 4; ++nj) s[mi][nj] = (f32x4)0.0f;
#pragma unroll
    for (int ki = 0; ki < 2; ++ki)
#pragma unroll
      for (int mi = 0; mi < 2; ++mi)
#pragma unroll
        for (int nj = 0; nj < 4; ++nj)
          s[mi][nj] = __builtin_amdgcn_mfma_f32_16x16x32_bf16(
              kA[mi][ki], qB[nj][ki], s[mi][nj], 0, 0, 0);

    // softmax numerator from u16 bias regs + lane-local pack to B-frag
    unsigned pw[4][4];
#pragma unroll
    for (int mi = 0; mi < 2; ++mi)
#pragma unroll
      for (int nj = 0; nj < 4; ++nj) {
        float p4[4];
#pragma unroll
        for (int r = 0; r < 4; ++r) {
          unsigned xr = (((r & 2) ? w[mi][nj].y : w[mi][nj].x) >>
                         ((r & 1) * 16)) & 0xFFFFu;
          float dv = __half2float(__ushort_as_half(
              (unsigned short)(xr & 0xFFFEu)));
          float tb = fmaf(s[mi][nj][r], sc2, msv[mi][r]);
          tb = fmaf(dv, ld2, tb);
          tb += (xr & 1u) ? la2 : 0.0f;
          p4[r] = __builtin_amdgcn_exp2f(tb);
        }
        rs[nj] += (p4[0] + p4[1]) + (p4[2] + p4[3]);
        pw[nj][mi * 2]     = pk2(p4[0], p4[1]);
        pw[nj][mi * 2 + 1] = pk2(p4[2], p4[3]);
      }
    bf16x8 pB[4];
#pragma unroll
    for (int nj = 0; nj < 4; ++nj) {
      union { unsigned u[4]; bf16x8 v; } pc;
      pc.u[0] = pw[nj][0]; pc.u[1] = pw[nj][1];
      pc.u[2] = pw[nj][2]; pc.u[3] = pw[nj][3];
      pB[nj] = pc.v;
    }

    // PV (phi cancels between pre-permuted V and lane-local P)
#pragma unroll
    for (int md = 0; md < 4; ++md)
#pragma unroll
      for (int nj = 0; nj < 4; ++nj)
        o[md][nj] = __builtin_amdgcn_mfma_f32_16x16x32_bf16(
            vA[md], pB[nj], o[md][nj], 0, 0, 0);
    // no barrier — waves fully independent until the merge
  }

  __syncthreads();  // all waves done with private staging before mgbuf alias
  const int hs = wid & 1;
  if (kh == 1) {
#pragma unroll
    for (int md = 0; md < 4; ++md)
#pragma unroll
      for (int nj = 0; nj < 4; ++nj)
#pragma unroll
        for (int r = 0; r < 4; ++r)
          mgbuf[hs * 4352 + ((md * 4 + nj) * 4 + r) * 64 + lane] = o[md][nj][r];
#pragma unroll
    for (int nj = 0; nj < 4; ++nj)
      mgbuf[hs * 4352 + (64 + nj) * 64 + lane] = rs[nj];
  }
  __syncthreads();
  if (kh == 0) {
#pragma unroll
    for (int md = 0; md < 4; ++md)
#pragma unroll
      for (int nj = 0; nj < 4; ++nj)
#pragma unroll
        for (int r = 0; r < 4; ++r)
          o[md][nj][r] += mgbuf[hs * 4352 + ((md * 4 + nj) * 4 + r) * 64 + lane];
    float inv[4];
#pragma unroll
    for (int nj = 0; nj < 4; ++nj) {
      rs[nj] += mgbuf[hs * 4352 + (64 + nj) * 64 + lane];
      rs[nj] += __shfl_xor(rs[nj], 16);
      rs[nj] += __shfl_xor(rs[nj], 32);
      inv[nj] = __builtin_amdgcn_rcpf(rs[nj]);
    }
#pragma unroll
    for (int md = 0; md < 4; ++md)
#pragma unroll
      for (int nj = 0; nj < 4; ++nj) {
        int l = q0 + nj * 16 + lo;
        uint2 st = { pk2(o[md][nj][0] * inv[nj], o[md][nj][1] * inv[nj]),
                     pk2(o[md][nj][2] * inv[nj], o[md][nj][3] * inv[nj]) };
        *(uint2*)&ao[((size_t)b * LL + l) * DM + h * DH + md * 16 + quad * 4] = st;
      }
  }
}

// ---------------- K3: output projection, barrier-free K-loop (r10) ---------
__global__ __launch_bounds__(256) void oproj(
    const unsigned short* __restrict__ ao, const unsigned short* __restrict__ wob,
    float* __restrict__ out)
{
  const int m0 = blockIdx.y * 128;
  const int n0 = blockIdx.x * 64;
  __shared__ __align__(16) char arena[81920];
  const int tid = threadIdx.x;
  const int wid = tid >> 6;
  const int lane = tid & 63;
  const int lo = lane & 15;
  const int quad = lane >> 4;
  char* xpriv = arena + 65536 + wid * 4096;

  f32x4 acc[2][4];
#pragma unroll
  for (int mi = 0; mi < 2; ++mi)
#pragma unroll
    for (int ni = 0; ni < 4; ++ni) acc[mi][ni] = (f32x4)0.0f;

#pragma unroll
  for (int j = 0; j < 16; ++j) {
    int idx = j * 256 + tid, r = idx >> 6, c = idx & 63;
    async_copy16(arena + j * 4096 + wid * 1024,
                 wob + (size_t)(n0 + r) * DM + ((c ^ (r & 15)) * 8));
  }
#pragma unroll
  for (int j = 0; j < 2; ++j) {
    int idx = j * 64 + lane, r = idx >> 2, c = idx & 3;
    async_copy16(xpriv + j * 1024,
                 ao + (size_t)(m0 + wid * 32 + r) * DM + ((c ^ (r & 3)) * 8));
  }
  __syncthreads();  // the only barrier

  const unsigned short* Wb = (const unsigned short*)arena;
  for (int it = 0; it < 16; ++it) {
    const int p = it & 1;
    if (it < 15) {
      const int kk = (it + 1) * 32;
#pragma unroll
      for (int j = 0; j < 2; ++j) {
        int idx = j * 64 + lane, r = idx >> 2, c = idx & 3;
        async_copy16(xpriv + (1 - p) * 2048 + j * 1024,
                     ao + (size_t)(m0 + wid * 32 + r) * DM + kk +
                         ((c ^ (r & 3)) * 8));
      }
      asm volatile("" ::: "memory");
      asm volatile("s_waitcnt vmcnt(2)" ::: "memory");
    } else {
      asm volatile("s_waitcnt vmcnt(0)" ::: "memory");
    }
    const unsigned short* Ab = (const unsigned short*)(xpriv + p * 2048);
    bf16x8 a[2], bfr[4];
#pragma unroll
    for (int mi = 0; mi < 2; ++mi) {
      int R = mi * 16 + lo;
      a[mi] = *(const bf16x8*)&Ab[R * 32 + ((quad ^ (R & 3)) * 8)];
    }
#pragma unroll
    for (int ni = 0; ni < 4; ++ni) {
      int N = ni * 16 + lo;
      bfr[ni] = *(const bf16x8*)&Wb[N * 512 + (((it * 4 + quad) ^ (N & 15)) * 8)];
    }
#pragma unroll
    for (int mi = 0; mi < 2; ++mi)
#pragma unroll
      for (int ni = 0; ni < 4; ++ni)
        acc[mi][ni] = __builtin_amdgcn_mfma_f32_16x16x32_bf16(
            a[mi], bfr[ni], acc[mi][ni], 0, 0, 0);
  }

#pragma unroll
  for (int mi = 0; mi < 2; ++mi)
#pragma unroll
    for (int ni = 0; ni < 4; ++ni)
#pragma unroll
      for (int r = 0; r < 4; ++r)
        out[(size_t)(m0 + wid * 32 + mi * 16 + quad * 4 + r) * DM +
            n0 + ni * 16 + lo] = acc[mi][ni][r];
}

extern "C" void kernel_launch(void* const* d_in, const int* in_sizes, int n_in,
                              void* d_out, int out_size, void* d_ws, size_t ws_size,
                              hipStream_t stream) {
  const float* qin = (const float*)d_in[0];
  const float* kin = (const float*)d_in[1];
  const float* vin = (const float*)d_in[2];
  const int*   msk = (const int*)d_in[3];
  const float* adj = (const float*)d_in[4];
  const float* dis = (const float*)d_in[5];
  const float* wq  = (const float*)d_in[6];
  const float* wk  = (const float*)d_in[7];
  const float* wv  = (const float*)d_in[8];
  const float* wo  = (const float*)d_in[9];
  const float* la  = (const float*)d_in[10];
  const float* ld  = (const float*)d_in[11];
  float* out = (float*)d_out;

  const size_t tensb = (size_t)BB * HH * LL * DH;   // 4,194,304
  const size_t xsz   = (size_t)BB * LL * DIN;       // 2,097,152
  unsigned short* qb  = (unsigned short*)d_ws;
  unsigned short* kb  = qb + tensb;
  unsigned short* vt  = kb + tensb;
  unsigned short* ao  = vt + tensb;                 // (B,L,512) bf16
  unsigned short* xq  = ao;                         // alias (dead until attn)
  unsigned short* xk  = ao + xsz;
  unsigned short* xv  = ao + tensb;
  unsigned short* wqb = xv + xsz;
  unsigned short* wkb = wqb + (size_t)DM * DIN;
  unsigned short* wvb = wkb + (size_t)DM * DIN;
  unsigned short* wob = wvb + (size_t)DM * DIN;
  float*          mdd = (float*)(wob + (size_t)DM * DM);
  unsigned short* bpk = (unsigned short*)(mdd + (size_t)BB * LL);  // 16.8 MB

  prep<<<dim3(10888), 256, 0, stream>>>(qin, kin, vin, wq, wk, wv, wo, msk,
                                        adj, dis,
                                        xq, xk, xv, wqb, wkb, wvb, wob, mdd, bpk);
  qkv_proj<<<dim3(8, 64, 3), 256, 0, stream>>>(xq, xk, xv, wqb, wkb, wvb, qb, kb, vt);
  attn<<<dim3(512), 256, 0, stream>>>(qb, kb, vt, mdd, bpk, la, ld, ao);
  oproj<<<dim3(8, 64), 256, 0, stream>>>(ao, wob, out);
}

// Round 15
// 226.208 us; speedup vs baseline: 1.0240x; 1.0240x over previous
//
#include <hip/hip_runtime.h>
#include <hip/hip_fp16.h>

#define BB 8
#define LL 1024
#define DIN 256
#define DM 512
#define HH 8
#define DH 64

typedef __attribute__((ext_vector_type(8))) short bf16x8;
typedef __attribute__((ext_vector_type(4))) float f32x4;

__device__ __forceinline__ unsigned short f2bf(float f) {
  union { float f; unsigned u; } c; c.f = f;
  unsigned u = c.u;
  return (unsigned short)((u + 0x7fffu + ((u >> 16) & 1u)) >> 16);
}

#if defined(__has_builtin)
#if __has_builtin(__builtin_amdgcn_cvt_pk_bf16_f32)
#define HAS_PK_BF16 1
#endif
#endif

#if defined(HAS_PK_BF16)
typedef __bf16 bf2 __attribute__((ext_vector_type(2)));
__device__ __forceinline__ unsigned pk2(float lo, float hi) {
  union { bf2 v; unsigned u; } c;
  c.v = __builtin_amdgcn_cvt_pk_bf16_f32(lo, hi);
  return c.u;
}
#else
__device__ __forceinline__ unsigned pk2(float lo, float hi) {
  return ((unsigned)f2bf(hi) << 16) | f2bf(lo);
}
#endif

// 16-bit bias pack: dis as f16 rounded to the 15-bit (even-LSB) grid,
// binary adj in the stolen LSB (validated r12: absmax unchanged).
__device__ __forceinline__ unsigned pk16(float a, float d) {
  unsigned v = (unsigned)__half_as_ushort(__float2half_rn(d));
  v = (v + 1u) & 0xFFFEu;           // round-to-nearest on 15-bit grid
  return v | (a > 0.5f ? 1u : 0u);
}
__device__ __forceinline__ unsigned pk16x2(float a0, float d0,
                                           float a1, float d1) {
  return pk16(a0, d0) | (pk16(a1, d1) << 16);
}

// async global -> LDS DMA, 16 B/lane; LDS dest = wave-uniform base + lane*16
__device__ __forceinline__ void async_copy16(void* lds, const void* g) {
  __builtin_amdgcn_global_load_lds(
      (const __attribute__((address_space(1))) unsigned*)g,
      (__attribute__((address_space(3))) unsigned*)lds, 16, 0, 0);
}

// ---------------- K0: merged precast (u16 bias pack) ----------------
__global__ __launch_bounds__(256) void prep(
    const float* __restrict__ qin, const float* __restrict__ kin,
    const float* __restrict__ vin,
    const float* __restrict__ wq, const float* __restrict__ wk,
    const float* __restrict__ wv, const float* __restrict__ wo,
    const int* __restrict__ msk,
    const float* __restrict__ adj, const float* __restrict__ dis,
    unsigned short* __restrict__ xq, unsigned short* __restrict__ xk,
    unsigned short* __restrict__ xv,
    unsigned short* __restrict__ wqb, unsigned short* __restrict__ wkb,
    unsigned short* __restrict__ wvb, unsigned short* __restrict__ wob,
    float* __restrict__ mad, unsigned short* __restrict__ bp)
{
  int t = blockIdx.x * 256 + threadIdx.x;
  const int XS = 524288, WS = 32768;
  if (t < 3 * XS) {
    int seg = t >> 19, off = t & (XS - 1);
    const float* s = (seg == 0) ? qin : (seg == 1) ? kin : vin;
    unsigned short* d = (seg == 0) ? xq : (seg == 1) ? xk : xv;
    float4 f = ((const float4*)s)[off];
    uint2 o = { pk2(f.x, f.y), pk2(f.z, f.w) };
    ((uint2*)d)[off] = o;
    return;
  }
  t -= 3 * XS;
  if (t < 3 * WS) {
    int seg = t >> 15, off = t & (WS - 1);
    const float* s = (seg == 0) ? wq : (seg == 1) ? wk : wv;
    unsigned short* d = (seg == 0) ? wqb : (seg == 1) ? wkb : wvb;
    float4 f = ((const float4*)s)[off];
    uint2 o = { pk2(f.x, f.y), pk2(f.z, f.w) };
    ((uint2*)d)[off] = o;
    return;
  }
  t -= 3 * WS;
  if (t < 65536) {
    float4 f = ((const float4*)wo)[t];
    uint2 o = { pk2(f.x, f.y), pk2(f.z, f.w) };
    ((uint2*)wob)[t] = o;
    return;
  }
  t -= 65536;
  if (t < 2048) {
    int4 m = ((const int4*)msk)[t];
    float4 f = { m.x ? 0.0f : -30000.0f, m.y ? 0.0f : -30000.0f,
                 m.z ? 0.0f : -30000.0f, m.w ? 0.0f : -30000.0f };
    ((float4*)mad)[t] = f;
    return;
  }
  t -= 2048;  // u16 bias pack: 1,048,576 threads x 8 elements
  if (t < 1048576) {
    float4 a0 = ((const float4*)adj)[t * 2];
    float4 a1 = ((const float4*)adj)[t * 2 + 1];
    float4 d0 = ((const float4*)dis)[t * 2];
    float4 d1 = ((const float4*)dis)[t * 2 + 1];
    uint4 o = { pk16x2(a0.x, d0.x, a0.y, d0.y),
                pk16x2(a0.z, d0.z, a0.w, d0.w),
                pk16x2(a1.x, d1.x, a1.y, d1.y),
                pk16x2(a1.z, d1.z, a1.w, d1.w) };
    ((uint4*)bp)[t] = o;
  }
}

// ---------------- K1: QKV projection, barrier-free K-loop (r10) ------------
__global__ __launch_bounds__(256) void qkv_proj(
    const unsigned short* __restrict__ xq, const unsigned short* __restrict__ xk,
    const unsigned short* __restrict__ xv,
    const unsigned short* __restrict__ wqb, const unsigned short* __restrict__ wkb,
    const unsigned short* __restrict__ wvb,
    unsigned short* __restrict__ qb, unsigned short* __restrict__ kb,
    unsigned short* __restrict__ vt)
{
  const int t = blockIdx.z;
  const unsigned short* __restrict__ X = (t == 0) ? xq : (t == 1) ? xk : xv;
  const unsigned short* __restrict__ W = (t == 0) ? wqb : (t == 1) ? wkb : wvb;
  const int m0 = blockIdx.y * 128;
  const int h  = blockIdx.x;
  // arena: W static 32768 | X 4 waves x (2 parity x 2048) = 49152 B
  __shared__ __align__(16) char arena[49152];
  const int tid = threadIdx.x;
  const int wid = tid >> 6;
  const int lane = tid & 63;
  const int lo = lane & 15;
  const int quad = lane >> 4;
  char* xpriv = arena + 32768 + wid * 4096;

  f32x4 acc[2][4];
#pragma unroll
  for (int mi = 0; mi < 2; ++mi)
#pragma unroll
    for (int ni = 0; ni < 4; ++ni) acc[mi][ni] = (f32x4)0.0f;

#pragma unroll
  for (int j = 0; j < 8; ++j) {
    int idx = j * 256 + tid, r = idx >> 5, c = idx & 31;
    async_copy16(arena + j * 4096 + wid * 1024,
                 W + (size_t)(h * 64 + r) * DIN + ((c ^ (r & 15)) * 8));
  }
#pragma unroll
  for (int j = 0; j < 2; ++j) {
    int idx = j * 64 + lane, r = idx >> 2, c = idx & 3;
    async_copy16(xpriv + j * 1024,
                 X + (size_t)(m0 + wid * 32 + r) * DIN + ((c ^ (r & 3)) * 8));
  }
  __syncthreads();  // drains W + X(0); the only barrier

  const unsigned short* Wb = (const unsigned short*)arena;
  for (int it = 0; it < 8; ++it) {
    const int p = it & 1;
    if (it < 7) {
      const int kk = (it + 1) * 32;
#pragma unroll
      for (int j = 0; j < 2; ++j) {
        int idx = j * 64 + lane, r = idx >> 2, c = idx & 3;
        async_copy16(xpriv + (1 - p) * 2048 + j * 1024,
                     X + (size_t)(m0 + wid * 32 + r) * DIN + kk +
                         ((c ^ (r & 3)) * 8));
      }
      asm volatile("" ::: "memory");
      asm volatile("s_waitcnt vmcnt(2)" ::: "memory");
    } else {
      asm volatile("s_waitcnt vmcnt(0)" ::: "memory");
    }
    const unsigned short* Ab = (const unsigned short*)(xpriv + p * 2048);
    bf16x8 a[2], bfr[4];
#pragma unroll
    for (int mi = 0; mi < 2; ++mi) {
      int R = mi * 16 + lo;
      a[mi] = *(const bf16x8*)&Ab[R * 32 + ((quad ^ (R & 3)) * 8)];
    }
#pragma unroll
    for (int ni = 0; ni < 4; ++ni) {
      int N = ni * 16 + lo;
      bfr[ni] = *(const bf16x8*)&Wb[N * 256 + (((it * 4 + quad) ^ (N & 15)) * 8)];
    }
#pragma unroll
    for (int mi = 0; mi < 2; ++mi)
#pragma unroll
      for (int ni = 0; ni < 4; ++ni)
        acc[mi][ni] = __builtin_amdgcn_mfma_f32_16x16x32_bf16(
            a[mi], bfr[ni], acc[mi][ni], 0, 0, 0);
  }

  const int b = m0 >> 10;
  const int lbase0 = (m0 & 1023) + wid * 32;
  if (t < 2) {
    unsigned short* dstp = (t == 0) ? qb : kb;
#pragma unroll
    for (int mi = 0; mi < 2; ++mi)
#pragma unroll
      for (int ni = 0; ni < 4; ++ni) {
        int d = ni * 16 + lo;
#pragma unroll
        for (int r = 0; r < 4; ++r) {
          int lb = lbase0 + mi * 16 + quad * 4 + r;
          dstp[((size_t)(b * HH + h) * LL + lb) * DH + d] = f2bf(acc[mi][ni][r]);
        }
      }
  } else {
#pragma unroll
    for (int mi = 0; mi < 2; ++mi)
#pragma unroll
      for (int ni = 0; ni < 4; ++ni) {
        int d = ni * 16 + lo;
        int lb = lbase0 + quad * 8 + mi * 4;  // phi-permuted within 32-block
        uint2 o = { pk2(acc[mi][ni][0], acc[mi][ni][1]),
                    pk2(acc[mi][ni][2], acc[mi][ni][3]) };
        *(uint2*)&vt[((size_t)(b * HH + h) * DH + d) * LL + lb] = o;
      }
  }
}

// ---------------- K2: attn, minimum-LDS wave-private pipeline --------------
// All staging wave-private, NO main-loop barrier. K SINGLE-buffered (4KB):
// K-DMA(t+1) issues only after lgkmcnt(0) drains tile-t ds_reads -> safe
// overwrite; its latency hides under softmax+PV. Bias (HBM) keeps a 2x2KB
// u16 double-buffer staged one tile ahead. LDS/wave = 8KB -> 32768/block.
// vmcnt FIFO audit (issue order/tile: biasDMA(t+1) 2 | V+mask 5 | [ds] |
// lgkm0; K-DMA(t+1) 4): tile-top wait vmcnt(7) retires K(t) (and bias(t),
// issued earlier); t=15: vmcnt(5). Prologue [bias0 2 | K0 4] satisfies the
// same count at t=0.
// grid 1024: idx = qt*32 + hg*8 + b. 4 waves: (h = hg*2 + wid&1, kh = wid>>1).
__global__ __launch_bounds__(256) void attn(
    const unsigned short* __restrict__ qb, const unsigned short* __restrict__ kb,
    const unsigned short* __restrict__ vt,
    const float* __restrict__ mad, const unsigned short* __restrict__ bp,
    const float* __restrict__ la_, const float* __restrict__ ld_,
    unsigned short* __restrict__ ao)
{
  const int bi = blockIdx.x;
  const int b  = bi & 7;
  const int hg = (bi >> 3) & 3;
  const int q0 = (bi >> 5) * 32;
  const int tid = threadIdx.x;
  const int wid = tid >> 6;
  const int lane = tid & 63;
  const int lo = lane & 15;
  const int quad = lane >> 4;
  const int h  = hg * 2 + (wid & 1);
  const int kh = wid >> 1;
  const int bh = b * HH + h;

  // arena: K single 4x4096 | bias dbuf 4x(2x2048) = 32768 B; merge alias after
  __shared__ __align__(16) char arena[32768];
  char* kpriv = arena + wid * 4096;            // wave-private single K buf
  char* bpriv = arena + 16384 + wid * 4096;    // wave-private bias, 2 parities
  float* mgbuf = (float*)arena;  // merge alias (post-loop, staging dead)

  const float LOG2E = 1.44269504f;
  const float la2 = la_[h] * LOG2E, ld2 = ld_[h] * LOG2E;
  const float sc2 = 0.125f * LOG2E;

  const unsigned short* qp = qb + ((size_t)bh * LL + q0) * DH;
  bf16x8 qB[2][2];
#pragma unroll
  for (int nj = 0; nj < 2; ++nj)
#pragma unroll
    for (int ki = 0; ki < 2; ++ki)
      qB[nj][ki] = *(const bf16x8*)&qp[(nj * 16 + lo) * DH + ki * 32 + quad * 8];

  const unsigned short* kp = kb + (size_t)bh * LL * DH;
  const unsigned short* vp = vt + (size_t)bh * DH * LL;
  const unsigned short* bpp = bp + ((size_t)b * LL + q0) * LL;
  const float* mp = mad + b * LL;

  f32x4 o[4][2];
  float rs[2] = {0.0f, 0.0f};
#pragma unroll
  for (int md = 0; md < 4; ++md)
#pragma unroll
    for (int nj = 0; nj < 2; ++nj) o[md][nj] = (f32x4)0.0f;

  const int kbeg = kh * (LL / 2);
  const int r8 = lane >> 3, p8 = lane & 7;
  const int br = lane >> 2;            // bias row within 16-row group
  const int bsw = ((((lane & 3) << 1) ^ (br & 6)) << 2);  // u16 col, swizzled

  // prologue: bias(0) -> parity 0 (2 ops), K(0) -> single buf (4 ops)
  {
    const unsigned short* bg = bpp + kh * (LL / 2);
#pragma unroll
    for (int j = 0; j < 2; ++j)
      async_copy16(bpriv + j * 1024, bg + (size_t)(j * 16 + br) * LL + bsw);
    const unsigned short* kg = kp + (size_t)kbeg * DH;
#pragma unroll
    for (int j = 0; j < 4; ++j)
      async_copy16(kpriv + j * 1024, kg + (j * 8 + r8) * 64 + ((p8 ^ r8) * 8));
  }
  // no barrier: wave-private staging, readiness via counted vmcnt

  for (int jt = 0; jt < 16; ++jt) {
    const int p = jt & 1;
    const int k0 = kbeg + jt * 32;

    // A: bias(t+1) DMA into alt parity (full-tile latency cover for HBM)
    if (jt < 15) {
      const unsigned short* bg = bpp + kh * (LL / 2) + (jt + 1) * 32;
#pragma unroll
      for (int j = 0; j < 2; ++j)
        async_copy16(bpriv + (1 - p) * 2048 + j * 1024,
                     bg + (size_t)(j * 16 + br) * LL + bsw);
    }

    // B: V (phi-ordered, 16B) + mask for THIS tile
    bf16x8 vA[4];
#pragma unroll
    for (int md = 0; md < 4; ++md)
      vA[md] = *(const bf16x8*)&vp[(md * 16 + lo) * LL + k0 + quad * 8];
    f32x4 msv[2];
#pragma unroll
    for (int mi = 0; mi < 2; ++mi)
      msv[mi] = *(const f32x4*)&mp[k0 + mi * 16 + quad * 4];
    asm volatile("" ::: "memory");

    // C: retire K(t) (+ bias(t), issued earlier in FIFO)
    if (jt < 15) {
      asm volatile("s_waitcnt vmcnt(7)" ::: "memory");
    } else {
      asm volatile("s_waitcnt vmcnt(5)" ::: "memory");
    }

    // D: all LDS reads for this tile -> regs
    bf16x8 kA[2][2];
#pragma unroll
    for (int mi = 0; mi < 2; ++mi)
#pragma unroll
      for (int ki = 0; ki < 2; ++ki)
        kA[mi][ki] = *(const bf16x8*)&((const unsigned short*)kpriv)
            [(mi * 16 + lo) * 64 + (((ki * 4 + quad) ^ (lo & 7)) * 8)];
    const unsigned short* bbf = (const unsigned short*)(bpriv + p * 2048);
    uint2 w[2][2];
#pragma unroll
    for (int mi = 0; mi < 2; ++mi)
#pragma unroll
      for (int nj = 0; nj < 2; ++nj)
        w[mi][nj] = *(const uint2*)&bbf[(nj * 16 + lo) * 32 +
                                        (((mi * 4 + quad) ^ (lo & 6)) << 2)];

    // E: LDS reads drained -> safe to overwrite single K buf with K(t+1)
    asm volatile("s_waitcnt lgkmcnt(0)" ::: "memory");
    if (jt < 15) {
      const unsigned short* kg = kp + (size_t)(k0 + 32) * DH;
#pragma unroll
      for (int j = 0; j < 4; ++j)
        async_copy16(kpriv + j * 1024,
                     kg + (j * 8 + r8) * 64 + ((p8 ^ r8) * 8));
    }
    asm volatile("" ::: "memory");

    // QK^T (register operands only)
    f32x4 s[2][2];
#pragma unroll
    for (int mi = 0; mi < 2; ++mi)
#pragma unroll
      for (int nj = 0; nj < 2; ++nj) s[mi][nj] = (f32x4)0.0f;
#pragma unroll
    for (int ki = 0; ki < 2; ++ki)
#pragma unroll
      for (int mi = 0; mi < 2; ++mi)
#pragma unroll
        for (int nj = 0; nj < 2; ++nj)
          s[mi][nj] = __builtin_amdgcn_mfma_f32_16x16x32_bf16(
              kA[mi][ki], qB[nj][ki], s[mi][nj], 0, 0, 0);

    // softmax numerator from u16 bias regs + lane-local pack to B-frag
    unsigned pw[2][4];
#pragma unroll
    for (int mi = 0; mi < 2; ++mi)
#pragma unroll
      for (int nj = 0; nj < 2; ++nj) {
        float p4[4];
#pragma unroll
        for (int r = 0; r < 4; ++r) {
          unsigned xr = (((r & 2) ? w[mi][nj].y : w[mi][nj].x) >>
                         ((r & 1) * 16)) & 0xFFFFu;
          float dv = __half2float(__ushort_as_half(
              (unsigned short)(xr & 0xFFFEu)));
          float tb = fmaf(s[mi][nj][r], sc2, msv[mi][r]);
          tb = fmaf(dv, ld2, tb);
          tb += (xr & 1u) ? la2 : 0.0f;
          p4[r] = __builtin_amdgcn_exp2f(tb);
        }
        rs[nj] += (p4[0] + p4[1]) + (p4[2] + p4[3]);
        pw[nj][mi * 2]     = pk2(p4[0], p4[1]);
        pw[nj][mi * 2 + 1] = pk2(p4[2], p4[3]);
      }
    bf16x8 pB[2];
#pragma unroll
    for (int nj = 0; nj < 2; ++nj) {
      union { unsigned u[4]; bf16x8 v; } pc;
      pc.u[0] = pw[nj][0]; pc.u[1] = pw[nj][1];
      pc.u[2] = pw[nj][2]; pc.u[3] = pw[nj][3];
      pB[nj] = pc.v;
    }

    // PV (phi cancels between pre-permuted V and lane-local P)
#pragma unroll
    for (int md = 0; md < 4; ++md)
#pragma unroll
      for (int nj = 0; nj < 2; ++nj)
        o[md][nj] = __builtin_amdgcn_mfma_f32_16x16x32_bf16(
            vA[md], pB[nj], o[md][nj], 0, 0, 0);
    // no barrier — waves fully independent until the merge
  }

  __syncthreads();  // all waves done with private staging before mgbuf alias
  const int hs = wid & 1;
  if (kh == 1) {
#pragma unroll
    for (int md = 0; md < 4; ++md)
#pragma unroll
      for (int nj = 0; nj < 2; ++nj)
#pragma unroll
        for (int r = 0; r < 4; ++r)
          mgbuf[hs * 2176 + ((md * 2 + nj) * 4 + r) * 64 + lane] = o[md][nj][r];
    mgbuf[hs * 2176 + 32 * 64 + lane] = rs[0];
    mgbuf[hs * 2176 + 33 * 64 + lane] = rs[1];
  }
  __syncthreads();
  if (kh == 0) {
#pragma unroll
    for (int md = 0; md < 4; ++md)
#pragma unroll
      for (int nj = 0; nj < 2; ++nj)
#pragma unroll
        for (int r = 0; r < 4; ++r)
          o[md][nj][r] += mgbuf[hs * 2176 + ((md * 2 + nj) * 4 + r) * 64 + lane];
    rs[0] += mgbuf[hs * 2176 + 32 * 64 + lane];
    rs[1] += mgbuf[hs * 2176 + 33 * 64 + lane];
    float inv[2];
#pragma unroll
    for (int nj = 0; nj < 2; ++nj) {
      rs[nj] += __shfl_xor(rs[nj], 16);
      rs[nj] += __shfl_xor(rs[nj], 32);
      inv[nj] = __builtin_amdgcn_rcpf(rs[nj]);
    }
#pragma unroll
    for (int md = 0; md < 4; ++md)
#pragma unroll
      for (int nj = 0; nj < 2; ++nj) {
        int l = q0 + nj * 16 + lo;
        uint2 st = { pk2(o[md][nj][0] * inv[nj], o[md][nj][1] * inv[nj]),
                     pk2(o[md][nj][2] * inv[nj], o[md][nj][3] * inv[nj]) };
        *(uint2*)&ao[((size_t)b * LL + l) * DM + h * DH + md * 16 + quad * 4] = st;
      }
  }
}

// ---------------- K3: output projection, barrier-free K-loop (r10) ---------
__global__ __launch_bounds__(256) void oproj(
    const unsigned short* __restrict__ ao, const unsigned short* __restrict__ wob,
    float* __restrict__ out)
{
  const int m0 = blockIdx.y * 128;
  const int n0 = blockIdx.x * 64;
  __shared__ __align__(16) char arena[81920];
  const int tid = threadIdx.x;
  const int wid = tid >> 6;
  const int lane = tid & 63;
  const int lo = lane & 15;
  const int quad = lane >> 4;
  char* xpriv = arena + 65536 + wid * 4096;

  f32x4 acc[2][4];
#pragma unroll
  for (int mi = 0; mi < 2; ++mi)
#pragma unroll
    for (int ni = 0; ni < 4; ++ni) acc[mi][ni] = (f32x4)0.0f;

#pragma unroll
  for (int j = 0; j < 16; ++j) {
    int idx = j * 256 + tid, r = idx >> 6, c = idx & 63;
    async_copy16(arena + j * 4096 + wid * 1024,
                 wob + (size_t)(n0 + r) * DM + ((c ^ (r & 15)) * 8));
  }
#pragma unroll
  for (int j = 0; j < 2; ++j) {
    int idx = j * 64 + lane, r = idx >> 2, c = idx & 3;
    async_copy16(xpriv + j * 1024,
                 ao + (size_t)(m0 + wid * 32 + r) * DM + ((c ^ (r & 3)) * 8));
  }
  __syncthreads();  // the only barrier

  const unsigned short* Wb = (const unsigned short*)arena;
  for (int it = 0; it < 16; ++it) {
    const int p = it & 1;
    if (it < 15) {
      const int kk = (it + 1) * 32;
#pragma unroll
      for (int j = 0; j < 2; ++j) {
        int idx = j * 64 + lane, r = idx >> 2, c = idx & 3;
        async_copy16(xpriv + (1 - p) * 2048 + j * 1024,
                     ao + (size_t)(m0 + wid * 32 + r) * DM + kk +
                         ((c ^ (r & 3)) * 8));
      }
      asm volatile("" ::: "memory");
      asm volatile("s_waitcnt vmcnt(2)" ::: "memory");
    } else {
      asm volatile("s_waitcnt vmcnt(0)" ::: "memory");
    }
    const unsigned short* Ab = (const unsigned short*)(xpriv + p * 2048);
    bf16x8 a[2], bfr[4];
#pragma unroll
    for (int mi = 0; mi < 2; ++mi) {
      int R = mi * 16 + lo;
      a[mi] = *(const bf16x8*)&Ab[R * 32 + ((quad ^ (R & 3)) * 8)];
    }
#pragma unroll
    for (int ni = 0; ni < 4; ++ni) {
      int N = ni * 16 + lo;
      bfr[ni] = *(const bf16x8*)&Wb[N * 512 + (((it * 4 + quad) ^ (N & 15)) * 8)];
    }
#pragma unroll
    for (int mi = 0; mi < 2; ++mi)
#pragma unroll
      for (int ni = 0; ni < 4; ++ni)
        acc[mi][ni] = __builtin_amdgcn_mfma_f32_16x16x32_bf16(
            a[mi], bfr[ni], acc[mi][ni], 0, 0, 0);
  }

#pragma unroll
  for (int mi = 0; mi < 2; ++mi)
#pragma unroll
    for (int ni = 0; ni < 4; ++ni)
#pragma unroll
      for (int r = 0; r < 4; ++r)
        out[(size_t)(m0 + wid * 32 + mi * 16 + quad * 4 + r) * DM +
            n0 + ni * 16 + lo] = acc[mi][ni][r];
}

extern "C" void kernel_launch(void* const* d_in, const int* in_sizes, int n_in,
                              void* d_out, int out_size, void* d_ws, size_t ws_size,
                              hipStream_t stream) {
  const float* qin = (const float*)d_in[0];
  const float* kin = (const float*)d_in[1];
  const float* vin = (const float*)d_in[2];
  const int*   msk = (const int*)d_in[3];
  const float* adj = (const float*)d_in[4];
  const float* dis = (const float*)d_in[5];
  const float* wq  = (const float*)d_in[6];
  const float* wk  = (const float*)d_in[7];
  const float* wv  = (const float*)d_in[8];
  const float* wo  = (const float*)d_in[9];
  const float* la  = (const float*)d_in[10];
  const float* ld  = (const float*)d_in[11];
  float* out = (float*)d_out;

  const size_t tensb = (size_t)BB * HH * LL * DH;   // 4,194,304
  const size_t xsz   = (size_t)BB * LL * DIN;       // 2,097,152
  unsigned short* qb  = (unsigned short*)d_ws;
  unsigned short* kb  = qb + tensb;
  unsigned short* vt  = kb + tensb;
  unsigned short* ao  = vt + tensb;                 // (B,L,512) bf16
  unsigned short* xq  = ao;                         // alias (dead until attn)
  unsigned short* xk  = ao + xsz;
  unsigned short* xv  = ao + tensb;
  unsigned short* wqb = xv + xsz;
  unsigned short* wkb = wqb + (size_t)DM * DIN;
  unsigned short* wvb = wkb + (size_t)DM * DIN;
  unsigned short* wob = wvb + (size_t)DM * DIN;
  float*          mdd = (float*)(wob + (size_t)DM * DM);
  unsigned short* bpk = (unsigned short*)(mdd + (size_t)BB * LL);  // 16.8 MB

  prep<<<dim3(10888), 256, 0, stream>>>(qin, kin, vin, wq, wk, wv, wo, msk,
                                        adj, dis,
                                        xq, xk, xv, wqb, wkb, wvb, wob, mdd, bpk);
  qkv_proj<<<dim3(8, 64, 3), 256, 0, stream>>>(xq, xk, xv, wqb, wkb, wvb, qb, kb, vt);
  attn<<<dim3(1024), 256, 0, stream>>>(qb, kb, vt, mdd, bpk, la, ld, ao);
  oproj<<<dim3(8, 64), 256, 0, stream>>>(ao, wob, out);
}